// Round 4
// baseline (291.221 us; speedup 1.0000x reference)
//
#include <hip/hip_runtime.h>
#include <hip/hip_bf16.h>

#define T_TOK 8192
#define DMODEL 1024
#define NEXP 128
#define CAP 256

typedef short s16x8 __attribute__((ext_vector_type(8)));
typedef float f32x4 __attribute__((ext_vector_type(4)));

__device__ __forceinline__ unsigned short f2bf(float f) {
    return __bfloat16_as_ushort(__float2bfloat16(f));   // compiles to v_cvt_pk_bf16_f32 pairs
}
__device__ __forceinline__ unsigned int pk2(unsigned short lo, unsigned short hi) {
    return (unsigned int)lo | ((unsigned int)hi << 16);
}
__device__ __forceinline__ float bf2f(unsigned short u) {
    union { unsigned int u; float f; } v; v.u = ((unsigned int)u) << 16; return v.f;
}

// ---------------- zero init: expert counters only ----------------
__global__ __launch_bounds__(128) void zero_cnt(int* __restrict__ cnt) {
    cnt[threadIdx.x] = 0;
}

// ---------------- gating: fp64 logits, top-2, weights, dispatch lists, x->bf16 ----------------
// block = 512 threads, 32 tokens per block, grid = 256  (8 waves/block -> 16 waves/CU)
__global__ __launch_bounds__(512) void gate_kernel(
    const float* __restrict__ x, const float* __restrict__ wg,
    unsigned short* __restrict__ xb, int* __restrict__ cnt,
    int* __restrict__ tokList, int* __restrict__ tokSlot,
    float* __restrict__ tokGate)
{
    __shared__ float xs[32][36];     // [tok][k]
    __shared__ float wgs[32][128];   // [k][e]
    __shared__ double ls[128][33];   // [e][tok] logits fp64

    int tid = threadIdx.x;
    int tok0 = blockIdx.x * 32;

    int tg = tid >> 6;          // 0..7  token phase
    int eg = tid & 63;          // expert pair base = eg*2
    int xtok = tid >> 4;        // 0..31 staging row
    int xoff = (tid & 15) * 2;  // staging col (2 floats)
    int wrow = tid >> 4;        // 0..31
    int wcol = (tid & 15) * 8;  // 8 floats

    double acc[4][2];
    #pragma unroll
    for (int j = 0; j < 4; j++) { acc[j][0] = 0.0; acc[j][1] = 0.0; }

    for (int k0 = 0; k0 < DMODEL; k0 += 32) {
        float2 xv = *(const float2*)(x + (size_t)(tok0 + xtok) * DMODEL + k0 + xoff);
        float4 wv4[2];
        #pragma unroll
        for (int c = 0; c < 2; c++)
            wv4[c] = *(const float4*)(wg + (size_t)(k0 + wrow) * NEXP + wcol + c * 4);

        __syncthreads();
        *(float2*)&xs[xtok][xoff] = xv;
        *(unsigned int*)(xb + (size_t)(tok0 + xtok) * DMODEL + k0 + xoff) = pk2(f2bf(xv.x), f2bf(xv.y));
        #pragma unroll
        for (int c = 0; c < 2; c++) *(float4*)&wgs[wrow][wcol + c * 4] = wv4[c];
        __syncthreads();

        #pragma unroll
        for (int k = 0; k < 32; k++) {
            float2 wv = *(const float2*)&wgs[k][eg * 2];
            double w0 = (double)wv.x, w1 = (double)wv.y;
            #pragma unroll
            for (int j = 0; j < 4; j++) {
                double xd = (double)xs[j * 8 + tg][k];
                acc[j][0] = fma(xd, w0, acc[j][0]);
                acc[j][1] = fma(xd, w1, acc[j][1]);
            }
        }
    }

    __syncthreads();
    #pragma unroll
    for (int j = 0; j < 4; j++) {
        ls[eg * 2][j * 8 + tg]     = acc[j][0];
        ls[eg * 2 + 1][j * 8 + tg] = acc[j][1];
    }
    __syncthreads();

    if (tid < 32) {
        int tok = tid;
        double m1 = -1e300, m2 = -1e300;
        int i1 = 0, i2 = 0;
        #pragma unroll 4
        for (int e = 0; e < NEXP; e++) {
            double v = ls[e][tok];
            if (v > m1) { m2 = m1; i2 = i1; m1 = v; i1 = e; }
            else if (v > m2) { m2 = v; i2 = e; }
        }
        double ed = exp(m2 - m1);            // <= 1
        float g1 = (float)(1.0 / (1.0 + ed));
        float g2 = (float)(ed / (1.0 + ed));
        int gtok = tok0 + tok;
        int s1 = atomicAdd(&cnt[i1], 1);
        int slot1 = -1;
        if (s1 < CAP) { slot1 = i1 * CAP + s1; tokList[slot1] = gtok; }
        int s2 = atomicAdd(&cnt[i2], 1);
        int slot2 = -1;
        if (s2 < CAP) { slot2 = i2 * CAP + s2; tokList[slot2] = gtok; }
        tokSlot[2 * gtok]     = slot1;
        tokSlot[2 * gtok + 1] = slot2;
        tokGate[2 * gtok]     = g1;
        tokGate[2 * gtok + 1] = g2;
    }
}

// ---------------- grouped expert GEMM -> yb bf16 (software-pipelined) ----------------
// grid = 128 experts * 8 n-blocks = 1024, block = 512 (8 waves)
// BM=256 (capacity), BN=128, BK=64.
#define LDS_STRIDE 72
__global__ __launch_bounds__(512, 4) void moe_gemm(
    const float* __restrict__ we, const unsigned short* __restrict__ xb,
    const int* __restrict__ cnt, const int* __restrict__ tokList,
    unsigned short* __restrict__ ybh)
{
    __shared__ unsigned short As[256 * LDS_STRIDE];  // 36 KB
    __shared__ unsigned short Bs[128 * LDS_STRIDE];  // 18 KB

    int b = blockIdx.x;
    int xcd = b & 7;
    int jj = b >> 3;
    int e = xcd * 16 + (jj >> 3);   // 8 n-blocks of one expert land on one XCD
    int nq = jj & 7;
    int nb = nq * 128;

    int count = cnt[e];
    if (count > CAP) count = CAP;

    int tid = threadIdx.x;
    int lane = tid & 63, wave = tid >> 6;
    int band = wave >> 1;   // 0..3 -> rows band*64..
    int nh = wave & 1;      // 0..1 -> cols nh*64..

    // fragment-granular row masking: this wave computes nmf 16-row fragments
    int mcount = count - band * 64;
    int nmf = (mcount + 15) >> 4;
    if (nmf < 0) nmf = 0;
    if (nmf > 4) nmf = 4;

    f32x4 acc[4][4] = {};

    // A staging: thread -> (row, half of 64 shorts) = 4 x uint4
    int ar = tid >> 1, ah = tid & 1;
    int atok = -1;
    if (ar < count) atok = tokList[e * CAP + ar];
    const unsigned short* asrc = xb + ((size_t)(atok < 0 ? 0 : atok) << 10) + ah * 32;
    unsigned short* adst = As + ar * LDS_STRIDE + ah * 32;

    // B staging: thread -> (n, k-quarter of 16)
    int bn = tid & 127, bkq = tid >> 7;
    const float* bsrc = we + ((size_t)e << 20) + (size_t)(bkq * 16) * DMODEL + nb + bn;
    unsigned short* bdst = Bs + bn * LDS_STRIDE + bkq * 16;

    // ---- prologue: issue loads for tile 0 ----
    uint4 fa0 = {0,0,0,0}, fa1 = {0,0,0,0}, fa2 = {0,0,0,0}, fa3 = {0,0,0,0};
    float fb[16];
    if (atok >= 0) {
        const uint4* p = (const uint4*)asrc;
        fa0 = p[0]; fa1 = p[1]; fa2 = p[2]; fa3 = p[3];
    }
    {
        const float* wp = bsrc;
        #pragma unroll
        for (int i = 0; i < 16; i++) fb[i] = wp[(size_t)i * DMODEL];
    }

    for (int t = 0; t < 16; ++t) {
        // convert current B tile (consumes fb)
        uint4 b0, b1;
        {
            unsigned short h[16];
            #pragma unroll
            for (int i = 0; i < 16; i++) h[i] = f2bf(fb[i]);
            b0.x = pk2(h[0], h[1]);   b0.y = pk2(h[2], h[3]);
            b0.z = pk2(h[4], h[5]);   b0.w = pk2(h[6], h[7]);
            b1.x = pk2(h[8], h[9]);   b1.y = pk2(h[10], h[11]);
            b1.z = pk2(h[12], h[13]); b1.w = pk2(h[14], h[15]);
        }

        __syncthreads();   // previous tile's LDS reads done
        *(uint4*)adst        = fa0;
        *(uint4*)(adst + 8)  = fa1;
        *(uint4*)(adst + 16) = fa2;
        *(uint4*)(adst + 24) = fa3;
        *(uint4*)bdst        = b0;
        *(uint4*)(bdst + 8)  = b1;
        __syncthreads();   // staging visible

        // issue next tile's global loads BEFORE the MFMA phase (latency hides under MFMA)
        if (t < 15) {
            int k1 = (t + 1) * 64;
            if (atok >= 0) {
                const uint4* p = (const uint4*)(asrc + k1);
                fa0 = p[0]; fa1 = p[1]; fa2 = p[2]; fa3 = p[3];
            }
            const float* wp = bsrc + (size_t)k1 * DMODEL;
            #pragma unroll
            for (int i = 0; i < 16; i++) fb[i] = wp[(size_t)i * DMODEL];
        }

        // MFMA on current LDS tile
        #pragma unroll
        for (int kk = 0; kk < 64; kk += 32) {
            int kr = kk + ((lane >> 4) << 3);
            s16x8 bf[4];
            const unsigned short* bbase = Bs + (size_t)(nh * 64 + (lane & 15)) * LDS_STRIDE + kr;
            #pragma unroll
            for (int nf = 0; nf < 4; nf++)
                bf[nf] = *(const s16x8*)(bbase + nf * 16 * LDS_STRIDE);
            const unsigned short* abase = As + (size_t)(band * 64 + (lane & 15)) * LDS_STRIDE + kr;
            #pragma unroll
            for (int mf = 0; mf < 4; mf++) {
                if (mf < nmf) {
                    s16x8 af = *(const s16x8*)(abase + mf * 16 * LDS_STRIDE);
                    #pragma unroll
                    for (int nf = 0; nf < 4; nf++)
                        acc[mf][nf] = __builtin_amdgcn_mfma_f32_16x16x32_bf16(af, bf[nf], acc[mf][nf], 0, 0, 0);
                }
            }
        }
    }

    // epilogue: bf16 stores into ybh[e*CAP + r]
    #pragma unroll
    for (int mf = 0; mf < 4; mf++) {
        if (mf < nmf) {
            #pragma unroll
            for (int j4 = 0; j4 < 4; j4++) {
                int r = band * 64 + mf * 16 + ((lane >> 4) << 2) + j4;
                if (r < count) {
                    unsigned short* yrow = ybh + (((size_t)(e * CAP + r)) << 10) + nb + nh * 64 + (lane & 15);
                    #pragma unroll
                    for (int nf = 0; nf < 4; nf++)
                        yrow[nf * 16] = f2bf(acc[mf][nf][j4]);
                }
            }
        }
    }
}

// ---------------- combine: out[tok] = g1*yb[slot1] + g2*yb[slot2] ----------------
// one wave per token; lane handles 16 elements. grid = 2048 x 256 thr.
__global__ __launch_bounds__(256) void combine_kernel(
    const unsigned short* __restrict__ ybh, const int* __restrict__ tokSlot,
    const float* __restrict__ tokGate, float* __restrict__ out)
{
    int tid = threadIdx.x;
    int tok = blockIdx.x * 4 + (tid >> 6);
    int lane = tid & 63;
    int sA = tokSlot[2 * tok], sB = tokSlot[2 * tok + 1];
    float gA = tokGate[2 * tok], gB = tokGate[2 * tok + 1];

    uint4 va[2] = {{0,0,0,0},{0,0,0,0}}, vb[2] = {{0,0,0,0},{0,0,0,0}};
    if (sA >= 0) {
        const uint4* p = (const uint4*)(ybh + ((size_t)sA << 10)) + lane * 2;
        va[0] = p[0]; va[1] = p[1];
    }
    if (sB >= 0) {
        const uint4* p = (const uint4*)(ybh + ((size_t)sB << 10)) + lane * 2;
        vb[0] = p[0]; vb[1] = p[1];
    }
    float4* o4 = (float4*)(out + ((size_t)tok << 10)) + lane * 4;
    #pragma unroll
    for (int h = 0; h < 2; h++) {
        const unsigned int* ua = (const unsigned int*)&va[h];
        const unsigned int* ub = (const unsigned int*)&vb[h];
        #pragma unroll
        for (int q = 0; q < 2; q++) {
            float4 o;
            unsigned int a0 = ua[q * 2], a1 = ua[q * 2 + 1];
            unsigned int b0 = ub[q * 2], b1 = ub[q * 2 + 1];
            o.x = gA * bf2f((unsigned short)(a0 & 0xFFFF)) + gB * bf2f((unsigned short)(b0 & 0xFFFF));
            o.y = gA * bf2f((unsigned short)(a0 >> 16))    + gB * bf2f((unsigned short)(b0 >> 16));
            o.z = gA * bf2f((unsigned short)(a1 & 0xFFFF)) + gB * bf2f((unsigned short)(b1 & 0xFFFF));
            o.w = gA * bf2f((unsigned short)(a1 >> 16))    + gB * bf2f((unsigned short)(b1 >> 16));
            o4[h * 2 + q] = o;
        }
    }
}

extern "C" void kernel_launch(void* const* d_in, const int* in_sizes, int n_in,
                              void* d_out, int out_size, void* d_ws, size_t ws_size,
                              hipStream_t stream) {
    const float* x  = (const float*)d_in[0];   // [4,2048,1024]
    const float* wg = (const float*)d_in[1];   // [1024,128]
    const float* we = (const float*)d_in[2];   // [128,1024,1024]
    float* out = (float*)d_out;                // [4,2048,1024]

    char* ws = (char*)d_ws;
    int*   cnt     = (int*)ws;                              // 512 B
    int*   tokList = (int*)(ws + 1024);                     // 128 KB  (slot -> token)
    int*   tokSlot = (int*)(ws + 1024 + 131072);            // 64 KB   (token -> 2 slots)
    float* tokGate = (float*)(ws + 1024 + 131072 + 65536);  // 64 KB   (token -> 2 gates)
    unsigned short* xb  = (unsigned short*)(ws + 524288);   // 16 MB   bf16 copy of x
    unsigned short* ybh = (unsigned short*)(ws + 524288 + 16777216);  // 32 MB expert outputs bf16 [E*CAP, D]

    zero_cnt<<<1, 128, 0, stream>>>(cnt);
    gate_kernel<<<256, 512, 0, stream>>>(x, wg, xb, cnt, tokList, tokSlot, tokGate);
    moe_gemm<<<1024, 512, 0, stream>>>(we, xb, cnt, tokList, ybh);
    combine_kernel<<<2048, 256, 0, stream>>>(ybh, tokSlot, tokGate, out);
}